// Round 1
// baseline (60.689 us; speedup 1.0000x reference)
//
#include <hip/hip_runtime.h>

// YOLO loss, replicating the reference exactly (including the pymax bug that
// uses pxc, and the anchor w/h swap).
// B=32, H=64, W=64, A=5, D=85 (5 box/conf + 80 class), fp32 in, scalar fp32 out.

constexpr int Bc = 32, Hc = 64, Wc = 64, Ac = 5, Dc = 85, Cc = 80;
constexpr int NCELL = Bc * Hc * Wc * Ac;   // 655360
constexpr float LAMDA_COORD = 5.0f;
constexpr float LAMDA_NOOBJ = 0.5f;
constexpr float LAMDA_OBJ   = 1.0f;
constexpr float LAMDA_CLASS = 1.0f;

__global__ void zero_kernel(float* out) {
    if (threadIdx.x == 0 && blockIdx.x == 0) out[0] = 0.0f;
}

__device__ __forceinline__ float smooth_l1(float x) {
    float ax = fabsf(x);
    return (ax < 1.0f) ? 0.5f * x * x : ax - 0.5f;
}

__global__ __launch_bounds__(256) void yolo_loss_kernel(
    const float* __restrict__ mo,     // model_output, flat (B,H,W,A,D)
    const float* __restrict__ lb,     // label, same layout
    const float* __restrict__ orig,   // (B,2)
    const float* __restrict__ anch,   // (A,2)
    float* __restrict__ result)
{
    int idx = blockIdx.x * blockDim.x + threadIdx.x;
    float loss = 0.0f;

    if (idx < NCELL) {
        long base = (long)idx * Dc;
        float lab4 = lb[base + 4];
        float out4 = mo[base + 4];

        if (lab4 == 0.0f) {
            // noobj: new_conf = lab4 * iou = 0  ->  lamda_noobj * out4^2
            loss = LAMDA_NOOBJ * out4 * out4;
        } else if (lab4 >= 1.0f) {
            // decompose idx -> (b, h, w, a); layout is (((b*H + h)*W + w)*A + a)
            int a = idx % Ac;
            int t = idx / Ac;
            int w = t % Wc; t /= Wc;
            int h = t % Hc;
            int b = t / Hc;

            float o0 = mo[base + 0], o1 = mo[base + 1];
            float o2 = mo[base + 2], o3 = mo[base + 3];
            float l0 = lb[base + 0], l1 = lb[base + 1];
            float l2 = lb[base + 2], l3 = lb[base + 3];

            float ylen = orig[b * 2 + 0] * (1.0f / Hc);
            float xlen = orig[b * 2 + 1] * (1.0f / Wc);
            float aw = anch[a * 2 + 1];   // reference swaps: aw = anchors[:,1]
            float ah = anch[a * 2 + 0];   //                  ah = anchors[:,0]

            float pxc = ((float)w + o0) * xlen;
            float pyc = ((float)h + o1) * ylen;
            float pw  = __expf(o2) * aw;
            float ph  = __expf(o3) * ah;
            float pxmin = pxc - pw * 0.5f, pxmax = pxc + pw * 0.5f;
            float pymin = pyc - ph * 0.5f;
            float pymax = pxc + ph * 0.5f;   // reference bug: uses pxc

            float txc = ((float)w + l0) * xlen;
            float tyc = ((float)h + l1) * ylen;
            float tw  = __expf(l2) * aw;
            float th  = __expf(l3) * ah;
            float txmin = txc - tw * 0.5f, txmax = txc + tw * 0.5f;
            float tymin = tyc - th * 0.5f, tymax = tyc + th * 0.5f;

            float iw = fmaxf(fminf(pxmax, txmax) - fmaxf(pxmin, txmin), 0.0f);
            float ih = fmaxf(fminf(pymax, tymax) - fmaxf(pymin, tymin), 0.0f);
            float inter  = iw * ih;
            float area_p = (pxmax - pxmin) * (pymax - pymin);
            float area_t = (txmax - txmin) * (tymax - tymin);
            float uni    = area_p + area_t - inter;
            float iou    = inter / uni;          // obj branch: union used as-is
            float new_conf = lab4 * iou;

            float d0 = o0 - l0, d1 = o1 - l1;
            float p1 = d0 * d0 + d1 * d1;
            float p2 = smooth_l1(o2 - l2) + smooth_l1(o3 - l3);
            float dc = out4 - new_conf;
            float p3 = dc * dc;

            float p5 = 0.0f;
            #pragma unroll 8
            for (int c = 0; c < Cc; ++c) {
                float d = mo[base + 5 + c] - lb[base + 5 + c];
                p5 += d * d;
            }

            loss = LAMDA_COORD * (p1 + p2) + LAMDA_OBJ * p3 + LAMDA_CLASS * p5;
        }
        // cells with 0 < lab4 < 1 contribute nothing (objf=noobjf=0) — none exist here
    }

    // wave (64-lane) reduction
    #pragma unroll
    for (int off = 32; off > 0; off >>= 1)
        loss += __shfl_down(loss, off);

    __shared__ float smem[4];
    int lane = threadIdx.x & 63;
    int wid  = threadIdx.x >> 6;
    if (lane == 0) smem[wid] = loss;
    __syncthreads();
    if (threadIdx.x == 0) {
        float tot = smem[0] + smem[1] + smem[2] + smem[3];
        atomicAdd(result, tot);
    }
}

extern "C" void kernel_launch(void* const* d_in, const int* in_sizes, int n_in,
                              void* d_out, int out_size, void* d_ws, size_t ws_size,
                              hipStream_t stream) {
    const float* mo   = (const float*)d_in[0];
    const float* lb   = (const float*)d_in[1];
    const float* orig = (const float*)d_in[2];
    const float* anch = (const float*)d_in[3];
    float* result = (float*)d_out;

    zero_kernel<<<1, 64, 0, stream>>>(result);

    int block = 256;
    int grid = (NCELL + block - 1) / block;   // 2560
    yolo_loss_kernel<<<grid, block, 0, stream>>>(mo, lb, orig, anch, result);
}